// Round 3
// baseline (32.658 us; speedup 1.0000x reference)
//
#include <hip/hip_runtime.h>

#define BB 32
#define NN 1024
#define DD 256

// ---------------- fused kernel with inline grid barrier ----------------
// 1024 blocks x 256 threads = 4 blocks/CU on 256 CUs (co-resident via
// cooperative launch). Each wave holds 16 rows in registers; the grid
// barrier is hand-rolled inline atomics (NO __ockl_grid_sync call), so
// there is no call-ABI boundary forcing the rows to spill.
#define NSLICE 64                 // 2 tensors * 32 batches
#define BPS 16                    // blocks per slice
#define NBLOCKS (NSLICE * BPS)    // 1024
#define RPB 64                    // rows per block
#define RPW 16                    // rows per wave (4 waves/block)

// ws layout: [64B barrier (memset 0 each launch)] [1 MB partial]
#define WS_BARRIER_BYTES 64
#define WS_NEEDED (WS_BARRIER_BYTES + (size_t)BPS * NSLICE * DD * sizeof(float))

__global__ __launch_bounds__(256, 4)
void fused_kernel(const float* __restrict__ x, const float* __restrict__ y,
                  unsigned int* __restrict__ bar,  // bar[0]=count, bar[1]=flag
                  float* __restrict__ partial,     // [BPS][NSLICE][DD]
                  float* __restrict__ out) {
    const int bid   = blockIdx.x;
    const int slice = bid / BPS;        // t*32 + b
    const int chunk = bid % BPS;
    const int t     = slice >> 5;       // 0 = x rows, 1 = y rows
    const int b     = slice & 31;
    const int lane  = threadIdx.x & 63;
    const int wave  = threadIdx.x >> 6; // 0..3
    const int d     = threadIdx.x;      // 0..255

    const int row0 = chunk * RPB + wave * RPW;
    const float4* srcv = reinterpret_cast<const float4*>(
        (t == 0 ? x : y) + (size_t)b * NN * DD) + (size_t)row0 * (DD / 4) + lane;

    // ---- phase 1: stream 16 rows into registers, column-sum on the way ----
    float4 v[RPW];
    float4 p = make_float4(0.f, 0.f, 0.f, 0.f);
    #pragma unroll
    for (int r = 0; r < RPW; ++r) {
        v[r] = srcv[(size_t)r * (DD / 4)];
        p.x += v[r].x; p.y += v[r].y; p.z += v[r].z; p.w += v[r].w;
    }

    // Pin the rows: opaque origin, cannot be rematerialized after the barrier.
    #pragma unroll
    for (int r = 0; r < RPW; ++r) {
        asm volatile("" : "+v"(v[r].x), "+v"(v[r].y), "+v"(v[r].z), "+v"(v[r].w));
    }

    __shared__ float lds[4][DD];        // 4 KB
    *reinterpret_cast<float4*>(&lds[wave][lane * 4]) = p;
    __syncthreads();
    float ps = lds[0][d] + lds[1][d] + lds[2][d] + lds[3][d];
    partial[((size_t)chunk * NSLICE + slice) * DD + d] = ps;

    // ---- inline grid barrier (counter + release flag, agent scope) ----
    __threadfence();                    // release: partial stores visible
    __syncthreads();                    // whole block done before arriving
    if (threadIdx.x == 0) {
        unsigned prev = __hip_atomic_fetch_add(&bar[0], 1u,
                            __ATOMIC_ACQ_REL, __HIP_MEMORY_SCOPE_AGENT);
        if (prev == NBLOCKS - 1) {
            __hip_atomic_store(&bar[1], 1u,
                               __ATOMIC_RELEASE, __HIP_MEMORY_SCOPE_AGENT);
        } else {
            while (__hip_atomic_load(&bar[1],
                       __ATOMIC_ACQUIRE, __HIP_MEMORY_SCOPE_AGENT) == 0u)
                __builtin_amdgcn_s_sleep(2);
        }
    }
    __syncthreads();
    __threadfence();                    // acquire: see other blocks' partials

    // ---- phase 2: finish opposite-tensor sum, dot register-held rows ----
    const int opp = slice ^ 32;         // flip tensor, same batch
    const float* pp = partial + (size_t)opp * DD + d;
    float s = 0.f;
    #pragma unroll
    for (int k = 0; k < BPS; ++k) s += pp[(size_t)k * NSLICE * DD];
    lds[0][d] = s;                      // safe: phase-1 lds reads long done
    __syncthreads();

    const float4 sv = *reinterpret_cast<const float4*>(&lds[0][lane * 4]);

    // t==0 (x rows): colsum -> out[b][1024+n]; t==1 (y rows): rowsum -> out[b][m]
    float* outp = out + (size_t)b * 2048 + (t == 0 ? 1024 : 0) + row0;
    #pragma unroll
    for (int r = 0; r < RPW; ++r) {
        float dv = v[r].x * sv.x + v[r].y * sv.y + v[r].z * sv.z + v[r].w * sv.w;
        #pragma unroll
        for (int off = 32; off >= 1; off >>= 1)
            dv += __shfl_down(dv, off, 64);
        if (lane == 0) outp[r] = dv;
    }
}

// ---------------- fallback: proven two-kernel path ----------------
#define SPLIT 8
#define CHUNK (NN / SPLIT)

__global__ void colsum_partial_kernel(const float* __restrict__ x,
                                      const float* __restrict__ y,
                                      float* __restrict__ partial) {
    int bid = blockIdx.x;
    int t   = bid / (BB * SPLIT);
    int rem = bid % (BB * SPLIT);
    int b   = rem / SPLIT;
    int s   = rem % SPLIT;
    int d   = threadIdx.x;

    const float* src = (t == 0 ? x : y)
                     + (size_t)b * NN * DD + (size_t)s * CHUNK * DD + d;

    float a0 = 0.f, a1 = 0.f, a2 = 0.f, a3 = 0.f;
    #pragma unroll 4
    for (int n = 0; n < CHUNK; n += 4) {
        a0 += src[(size_t)(n + 0) * DD];
        a1 += src[(size_t)(n + 1) * DD];
        a2 += src[(size_t)(n + 2) * DD];
        a3 += src[(size_t)(n + 3) * DD];
    }
    partial[(((size_t)t * SPLIT + s) * BB + b) * DD + d] = (a0 + a1) + (a2 + a3);
}

#define RCHUNKS 16
#define ROWS_PER_BLOCK 64

__global__ void dots_kernel(const float* __restrict__ x,
                            const float* __restrict__ y,
                            const float* __restrict__ partial,
                            float* __restrict__ out) {
    int bid = blockIdx.x;
    int rc  = bid % RCHUNKS;
    int bt  = bid / RCHUNKS;
    int t   = bt & 1;
    int b   = bt >> 1;
    int d   = threadIdx.x;

    __shared__ float ssum[DD];
    {
        const float* p = partial + ((size_t)t * SPLIT * BB + b) * DD + d;
        float s = 0.f;
        #pragma unroll
        for (int k = 0; k < SPLIT; ++k) s += p[(size_t)k * BB * DD];
        ssum[d] = s;
    }
    __syncthreads();

    int lane = threadIdx.x & 63;
    int wave = threadIdx.x >> 6;

    float4 sv = *reinterpret_cast<const float4*>(&ssum[lane * 4]);
    const float* data = (t == 0 ? y : x) + (size_t)b * NN * DD;
    float* outp = out + (size_t)b * 2048 + (size_t)t * 1024;

    int r0 = rc * ROWS_PER_BLOCK + wave * 16;
    #pragma unroll 4
    for (int r = 0; r < 16; ++r) {
        int row = r0 + r;
        float4 w = *reinterpret_cast<const float4*>(&data[(size_t)row * DD + lane * 4]);
        float dotv = w.x * sv.x + w.y * sv.y + w.z * sv.z + w.w * sv.w;
        #pragma unroll
        for (int off = 32; off >= 1; off >>= 1)
            dotv += __shfl_down(dotv, off, 64);
        if (lane == 0) outp[row] = dotv;
    }
}

extern "C" void kernel_launch(void* const* d_in, const int* in_sizes, int n_in,
                              void* d_out, int out_size, void* d_ws, size_t ws_size,
                              hipStream_t stream) {
    const float* x = (const float*)d_in[0];
    const float* y = (const float*)d_in[1];
    float* out     = (float*)d_out;

    static int use_coop = -1;
    if (use_coop < 0) {
        int nb = 0;
        hipError_t e = hipOccupancyMaxActiveBlocksPerMultiprocessor(
            &nb, (const void*)fused_kernel, 256, 0);
        use_coop = (e == hipSuccess && nb >= 4 && ws_size >= WS_NEEDED) ? 1 : 0;
    }

    if (use_coop) {
        unsigned int* bar = (unsigned int*)d_ws;
        float* partial    = (float*)((char*)d_ws + WS_BARRIER_BYTES);
        hipMemsetAsync(d_ws, 0, WS_BARRIER_BYTES, stream);  // count/flag = 0
        void* args[] = { (void*)&x, (void*)&y, (void*)&bar,
                         (void*)&partial, (void*)&out };
        hipError_t e = hipLaunchCooperativeKernel(
            (const void*)fused_kernel, dim3(NBLOCKS), dim3(256), args, 0, stream);
        if (e == hipSuccess) return;
        use_coop = 0;                   // cooperative path unavailable: fall back
    }

    float* partial = (float*)d_ws;      // fallback layout: 512 KB at ws+0
    colsum_partial_kernel<<<2 * BB * SPLIT, 256, 0, stream>>>(x, y, partial);
    dots_kernel<<<BB * 2 * RCHUNKS, 256, 0, stream>>>(x, y, partial, out);
}

// Round 4
// 27.266 us; speedup vs baseline: 1.1978x; 1.1978x over previous
//
#include <hip/hip_runtime.h>

#define BB 32
#define NN 1024
#define DD 256

// ---------------- fused kernel, register-resident rows ----------------
// 1024 blocks x 256 threads = 4 blocks/CU on 256 CUs (co-resident via
// cooperative launch). Each wave holds 16 rows in registers across a
// per-slice sync. Pins carry a "memory" clobber: all pointers are
// __restrict__, so without it the compiler legally sinks the (register-only)
// pin asm + loads past the barrier atomics and re-reads 64 MB in phase 2
// (observed rounds 1-3: VGPR_Count stuck at 48 < 64 data regs).
#define NSLICE 64                 // 2 tensors * 32 batches
#define BPS 16                    // blocks per slice
#define NBLOCKS (NSLICE * BPS)    // 1024
#define RPB 64                    // rows per block
#define RPW 16                    // rows per wave (4 waves/block)

// ws layout: [64 counters, 64B apart -> 4 KB, memset 0 each launch][1 MB partial]
#define WS_CTR_STRIDE 16          // u32s per counter line (64 B)
#define WS_CTR_BYTES  (NSLICE * WS_CTR_STRIDE * 4)
#define WS_NEEDED (WS_CTR_BYTES + (size_t)BPS * NSLICE * DD * sizeof(float))

__global__ __launch_bounds__(256, 4)
void fused_kernel(const float* __restrict__ x, const float* __restrict__ y,
                  unsigned int* __restrict__ ctr,  // [NSLICE] stride 16 u32
                  float* __restrict__ partial,     // [BPS][NSLICE][DD]
                  float* __restrict__ out) {
    const int bid   = blockIdx.x;
    const int slice = bid / BPS;        // t*32 + b
    const int chunk = bid % BPS;
    const int t     = slice >> 5;       // 0 = x rows, 1 = y rows
    const int b     = slice & 31;
    const int lane  = threadIdx.x & 63;
    const int wave  = threadIdx.x >> 6; // 0..3
    const int d     = threadIdx.x;      // 0..255

    const int row0 = chunk * RPB + wave * RPW;
    const float4* srcv = reinterpret_cast<const float4*>(
        (t == 0 ? x : y) + (size_t)b * NN * DD) + (size_t)row0 * (DD / 4) + lane;

    // ---- phase 1: stream 16 rows into registers, column-sum on the way ----
    float4 v[RPW];
    float4 p = make_float4(0.f, 0.f, 0.f, 0.f);
    #pragma unroll
    for (int r = 0; r < RPW; ++r) {
        v[r] = srcv[(size_t)r * (DD / 4)];
        p.x += v[r].x; p.y += v[r].y; p.z += v[r].z; p.w += v[r].w;
    }

    // Pin rows in VGPRs. "memory" clobber: loads cannot sink below this,
    // pins cannot move across the barrier atomics below.
    #pragma unroll
    for (int r = 0; r < RPW; ++r) {
        asm volatile("" : "+v"(v[r].x), "+v"(v[r].y), "+v"(v[r].z), "+v"(v[r].w)
                         :: "memory");
    }
    __builtin_amdgcn_sched_barrier(0);

    __shared__ float lds[4][DD];        // 4 KB
    *reinterpret_cast<float4*>(&lds[wave][lane * 4]) = p;
    __syncthreads();
    float ps = lds[0][d] + lds[1][d] + lds[2][d] + lds[3][d];
    partial[((size_t)chunk * NSLICE + slice) * DD + d] = ps;

    // ---- per-slice sync: publish own partial, wait for opposite slice ----
    const int opp = slice ^ 32;         // flip tensor, same batch
    __threadfence();                    // release: partial stores visible
    __syncthreads();                    // whole block done before arriving
    if (threadIdx.x == 0) {
        __hip_atomic_fetch_add(&ctr[slice * WS_CTR_STRIDE], 1u,
                               __ATOMIC_RELEASE, __HIP_MEMORY_SCOPE_AGENT);
        while (__hip_atomic_load(&ctr[opp * WS_CTR_STRIDE],
                   __ATOMIC_ACQUIRE, __HIP_MEMORY_SCOPE_AGENT) < (unsigned)BPS)
            __builtin_amdgcn_s_sleep(2);
    }
    __syncthreads();
    __threadfence();                    // acquire: see opposite partials

    // ---- phase 2: finish opposite-tensor sum, dot register-held rows ----
    const float* pp = partial + (size_t)opp * DD + d;
    float s = 0.f;
    #pragma unroll
    for (int k = 0; k < BPS; ++k) s += pp[(size_t)k * NSLICE * DD];
    lds[0][d] = s;                      // safe: phase-1 lds reads long done
    __syncthreads();

    const float4 sv = *reinterpret_cast<const float4*>(&lds[0][lane * 4]);

    // t==0 (x rows): colsum -> out[b][1024+n]; t==1 (y rows): rowsum -> out[b][m]
    float* outp = out + (size_t)b * 2048 + (t == 0 ? 1024 : 0) + row0;
    #pragma unroll
    for (int r = 0; r < RPW; ++r) {
        float dv = v[r].x * sv.x + v[r].y * sv.y + v[r].z * sv.z + v[r].w * sv.w;
        #pragma unroll
        for (int off = 32; off >= 1; off >>= 1)
            dv += __shfl_down(dv, off, 64);
        if (lane == 0) outp[r] = dv;
    }
}

// ---------------- fallback: proven two-kernel path ----------------
#define SPLIT 8
#define CHUNK (NN / SPLIT)

__global__ void colsum_partial_kernel(const float* __restrict__ x,
                                      const float* __restrict__ y,
                                      float* __restrict__ partial) {
    int bid = blockIdx.x;
    int t   = bid / (BB * SPLIT);
    int rem = bid % (BB * SPLIT);
    int b   = rem / SPLIT;
    int s   = rem % SPLIT;
    int d   = threadIdx.x;

    const float* src = (t == 0 ? x : y)
                     + (size_t)b * NN * DD + (size_t)s * CHUNK * DD + d;

    float a0 = 0.f, a1 = 0.f, a2 = 0.f, a3 = 0.f;
    #pragma unroll 4
    for (int n = 0; n < CHUNK; n += 4) {
        a0 += src[(size_t)(n + 0) * DD];
        a1 += src[(size_t)(n + 1) * DD];
        a2 += src[(size_t)(n + 2) * DD];
        a3 += src[(size_t)(n + 3) * DD];
    }
    partial[(((size_t)t * SPLIT + s) * BB + b) * DD + d] = (a0 + a1) + (a2 + a3);
}

#define RCHUNKS 16
#define ROWS_PER_BLOCK 64

__global__ void dots_kernel(const float* __restrict__ x,
                            const float* __restrict__ y,
                            const float* __restrict__ partial,
                            float* __restrict__ out) {
    int bid = blockIdx.x;
    int rc  = bid % RCHUNKS;
    int bt  = bid / RCHUNKS;
    int t   = bt & 1;
    int b   = bt >> 1;
    int d   = threadIdx.x;

    __shared__ float ssum[DD];
    {
        const float* p = partial + ((size_t)t * SPLIT * BB + b) * DD + d;
        float s = 0.f;
        #pragma unroll
        for (int k = 0; k < SPLIT; ++k) s += p[(size_t)k * BB * DD];
        ssum[d] = s;
    }
    __syncthreads();

    int lane = threadIdx.x & 63;
    int wave = threadIdx.x >> 6;

    float4 sv = *reinterpret_cast<const float4*>(&ssum[lane * 4]);
    const float* data = (t == 0 ? y : x) + (size_t)b * NN * DD;
    float* outp = out + (size_t)b * 2048 + (size_t)t * 1024;

    int r0 = rc * ROWS_PER_BLOCK + wave * 16;
    #pragma unroll 4
    for (int r = 0; r < 16; ++r) {
        int row = r0 + r;
        float4 w = *reinterpret_cast<const float4*>(&data[(size_t)row * DD + lane * 4]);
        float dotv = w.x * sv.x + w.y * sv.y + w.z * sv.z + w.w * sv.w;
        #pragma unroll
        for (int off = 32; off >= 1; off >>= 1)
            dotv += __shfl_down(dotv, off, 64);
        if (lane == 0) outp[row] = dotv;
    }
}

extern "C" void kernel_launch(void* const* d_in, const int* in_sizes, int n_in,
                              void* d_out, int out_size, void* d_ws, size_t ws_size,
                              hipStream_t stream) {
    const float* x = (const float*)d_in[0];
    const float* y = (const float*)d_in[1];
    float* out     = (float*)d_out;

    static int use_coop = -1;
    if (use_coop < 0) {
        int nb = 0;
        hipError_t e = hipOccupancyMaxActiveBlocksPerMultiprocessor(
            &nb, (const void*)fused_kernel, 256, 0);
        use_coop = (e == hipSuccess && nb >= 4 && ws_size >= WS_NEEDED) ? 1 : 0;
    }

    if (use_coop) {
        unsigned int* ctr = (unsigned int*)d_ws;
        float* partial    = (float*)((char*)d_ws + WS_CTR_BYTES);
        hipMemsetAsync(d_ws, 0, WS_CTR_BYTES, stream);  // zero slice counters
        void* args[] = { (void*)&x, (void*)&y, (void*)&ctr,
                         (void*)&partial, (void*)&out };
        hipError_t e = hipLaunchCooperativeKernel(
            (const void*)fused_kernel, dim3(NBLOCKS), dim3(256), args, 0, stream);
        if (e == hipSuccess) return;
        use_coop = 0;                   // cooperative path unavailable: fall back
    }

    float* partial = (float*)d_ws;      // fallback layout: 512 KB at ws+0
    colsum_partial_kernel<<<2 * BB * SPLIT, 256, 0, stream>>>(x, y, partial);
    dots_kernel<<<BB * 2 * RCHUNKS, 256, 0, stream>>>(x, y, partial, out);
}

// Round 5
// 27.108 us; speedup vs baseline: 1.2047x; 1.0058x over previous
//
#include <hip/hip_runtime.h>

#define BB 32
#define NN 1024
#define DD 256

// ---------------- fused kernel, register-resident rows ----------------
// 1024 blocks x 256 threads, co-resident via cooperative launch.
// Each wave holds 16 rows in registers across a per-slice sync (pinned by
// opaque asm; round-4 WRITE_SIZE showed no scratch traffic -> rows are
// carried in the unified VGPR/AGPR file). This round removes the heavy
// sync machinery: no __threadfence (L2 writeback/invalidate per block),
// no 1MB partial buffer + 16MB gather. Producers atomicAdd straight into
// fsum[slice][256] (device-scope fp32 atomics at the coherence point);
// consumers read ONE coherent float per thread.
#define NSLICE 64                 // 2 tensors * 32 batches
#define BPS 16                    // blocks per slice
#define NBLOCKS (NSLICE * BPS)    // 1024
#define RPB 64                    // rows per block
#define RPW 16                    // rows per wave (4 waves/block)

// ws layout: [64 counters, 64B apart -> 4 KB][fsum 64 KB]; memset 0 each launch
#define WS_CTR_STRIDE 16          // u32s per counter line (64 B)
#define WS_CTR_BYTES  (NSLICE * WS_CTR_STRIDE * 4)
#define WS_FSUM_BYTES (NSLICE * DD * 4)
#define WS_NEEDED     ((size_t)WS_CTR_BYTES + WS_FSUM_BYTES)

__global__ __launch_bounds__(256, 4)
void fused_kernel(const float* __restrict__ x, const float* __restrict__ y,
                  unsigned int* __restrict__ ctr,  // [NSLICE] stride 16 u32
                  float* __restrict__ fsum,        // [NSLICE][DD]
                  float* __restrict__ out) {
    const int bid   = blockIdx.x;
    const int slice = bid / BPS;        // 0..31 = x batches, 32..63 = y batches
    const int chunk = bid % BPS;
    const int t     = slice >> 5;       // 0 = x rows, 1 = y rows
    const int b     = slice & 31;
    const int lane  = threadIdx.x & 63;
    const int wave  = threadIdx.x >> 6; // 0..3
    const int d     = threadIdx.x;      // 0..255

    const int row0 = chunk * RPB + wave * RPW;
    const float4* srcv = reinterpret_cast<const float4*>(
        (t == 0 ? x : y) + (size_t)b * NN * DD) + (size_t)row0 * (DD / 4) + lane;

    // ---- phase 1: stream 16 rows into registers, column-sum on the way ----
    float4 v[RPW];
    float4 p = make_float4(0.f, 0.f, 0.f, 0.f);
    #pragma unroll
    for (int r = 0; r < RPW; ++r) {
        v[r] = srcv[(size_t)r * (DD / 4)];
        p.x += v[r].x; p.y += v[r].y; p.z += v[r].z; p.w += v[r].w;
    }

    // Pin rows: opaque origin + memory clobber so loads can't sink past here
    // and the pinned values must be carried across the sync.
    #pragma unroll
    for (int r = 0; r < RPW; ++r) {
        asm volatile("" : "+v"(v[r].x), "+v"(v[r].y), "+v"(v[r].z), "+v"(v[r].w)
                         :: "memory");
    }
    __builtin_amdgcn_sched_barrier(0);

    __shared__ float lds[4][DD];        // 4 KB
    *reinterpret_cast<float4*>(&lds[wave][lane * 4]) = p;
    __syncthreads();
    float ps = lds[0][d] + lds[1][d] + lds[2][d] + lds[3][d];

    // One device-scope fp32 atomicAdd per thread into the FINAL sum.
    __hip_atomic_fetch_add(&fsum[(size_t)slice * DD + d], ps,
                           __ATOMIC_RELAXED, __HIP_MEMORY_SCOPE_AGENT);

    // ---- per-slice sync: every wave drains its add at the barrier, then
    // thread 0 publishes arrival (release) and waits for the opposite slice.
    const int opp = slice ^ 32;         // flip tensor, same batch
    __syncthreads();                    // vmcnt(0) drain: block's adds complete
    if (threadIdx.x == 0) {
        __hip_atomic_fetch_add(&ctr[slice * WS_CTR_STRIDE], 1u,
                               __ATOMIC_RELEASE, __HIP_MEMORY_SCOPE_AGENT);
        while (__hip_atomic_load(&ctr[opp * WS_CTR_STRIDE],
                   __ATOMIC_ACQUIRE, __HIP_MEMORY_SCOPE_AGENT) < (unsigned)BPS)
            __builtin_amdgcn_s_sleep(2);
    }
    __syncthreads();

    // ---- phase 2: one coherent load per thread, broadcast via LDS, dots ----
    float s = __hip_atomic_load(&fsum[(size_t)opp * DD + d],
                                __ATOMIC_ACQUIRE, __HIP_MEMORY_SCOPE_AGENT);
    lds[0][d] = s;
    __syncthreads();

    const float4 sv = *reinterpret_cast<const float4*>(&lds[0][lane * 4]);

    // t==0 (x rows): colsum -> out[b][1024+n]; t==1 (y rows): rowsum -> out[b][m]
    float* outp = out + (size_t)b * 2048 + (t == 0 ? 1024 : 0) + row0;
    #pragma unroll
    for (int r = 0; r < RPW; ++r) {
        float dv = v[r].x * sv.x + v[r].y * sv.y + v[r].z * sv.z + v[r].w * sv.w;
        #pragma unroll
        for (int off = 32; off >= 1; off >>= 1)
            dv += __shfl_down(dv, off, 64);
        if (lane == 0) outp[r] = dv;
    }
}

// ---------------- fallback: proven two-kernel path ----------------
#define SPLIT 8
#define CHUNK (NN / SPLIT)

__global__ void colsum_partial_kernel(const float* __restrict__ x,
                                      const float* __restrict__ y,
                                      float* __restrict__ partial) {
    int bid = blockIdx.x;
    int t   = bid / (BB * SPLIT);
    int rem = bid % (BB * SPLIT);
    int b   = rem / SPLIT;
    int s   = rem % SPLIT;
    int d   = threadIdx.x;

    const float* src = (t == 0 ? x : y)
                     + (size_t)b * NN * DD + (size_t)s * CHUNK * DD + d;

    float a0 = 0.f, a1 = 0.f, a2 = 0.f, a3 = 0.f;
    #pragma unroll 4
    for (int n = 0; n < CHUNK; n += 4) {
        a0 += src[(size_t)(n + 0) * DD];
        a1 += src[(size_t)(n + 1) * DD];
        a2 += src[(size_t)(n + 2) * DD];
        a3 += src[(size_t)(n + 3) * DD];
    }
    partial[(((size_t)t * SPLIT + s) * BB + b) * DD + d] = (a0 + a1) + (a2 + a3);
}

#define RCHUNKS 16
#define ROWS_PER_BLOCK 64

__global__ void dots_kernel(const float* __restrict__ x,
                            const float* __restrict__ y,
                            const float* __restrict__ partial,
                            float* __restrict__ out) {
    int bid = blockIdx.x;
    int rc  = bid % RCHUNKS;
    int bt  = bid / RCHUNKS;
    int t   = bt & 1;
    int b   = bt >> 1;
    int d   = threadIdx.x;

    __shared__ float ssum[DD];
    {
        const float* p = partial + ((size_t)t * SPLIT * BB + b) * DD + d;
        float s = 0.f;
        #pragma unroll
        for (int k = 0; k < SPLIT; ++k) s += p[(size_t)k * BB * DD];
        ssum[d] = s;
    }
    __syncthreads();

    int lane = threadIdx.x & 63;
    int wave = threadIdx.x >> 6;

    float4 sv = *reinterpret_cast<const float4*>(&ssum[lane * 4]);
    const float* data = (t == 0 ? y : x) + (size_t)b * NN * DD;
    float* outp = out + (size_t)b * 2048 + (size_t)t * 1024;

    int r0 = rc * ROWS_PER_BLOCK + wave * 16;
    #pragma unroll 4
    for (int r = 0; r < 16; ++r) {
        int row = r0 + r;
        float4 w = *reinterpret_cast<const float4*>(&data[(size_t)row * DD + lane * 4]);
        float dotv = w.x * sv.x + w.y * sv.y + w.z * sv.z + w.w * sv.w;
        #pragma unroll
        for (int off = 32; off >= 1; off >>= 1)
            dotv += __shfl_down(dotv, off, 64);
        if (lane == 0) outp[row] = dotv;
    }
}

extern "C" void kernel_launch(void* const* d_in, const int* in_sizes, int n_in,
                              void* d_out, int out_size, void* d_ws, size_t ws_size,
                              hipStream_t stream) {
    const float* x = (const float*)d_in[0];
    const float* y = (const float*)d_in[1];
    float* out     = (float*)d_out;

    static int use_coop = -1;
    if (use_coop < 0) {
        int nb = 0;
        hipError_t e = hipOccupancyMaxActiveBlocksPerMultiprocessor(
            &nb, (const void*)fused_kernel, 256, 0);
        use_coop = (e == hipSuccess && nb >= 4 && ws_size >= WS_NEEDED) ? 1 : 0;
    }

    if (use_coop) {
        unsigned int* ctr = (unsigned int*)d_ws;
        float* fsum       = (float*)((char*)d_ws + WS_CTR_BYTES);
        hipMemsetAsync(d_ws, 0, WS_NEEDED, stream);   // zero counters + fsum
        void* args[] = { (void*)&x, (void*)&y, (void*)&ctr,
                         (void*)&fsum, (void*)&out };
        hipError_t e = hipLaunchCooperativeKernel(
            (const void*)fused_kernel, dim3(NBLOCKS), dim3(256), args, 0, stream);
        if (e == hipSuccess) return;
        use_coop = 0;                   // cooperative path unavailable: fall back
    }

    float* partial = (float*)d_ws;      // fallback layout: 512 KB at ws+0
    colsum_partial_kernel<<<2 * BB * SPLIT, 256, 0, stream>>>(x, y, partial);
    dots_kernel<<<BB * 2 * RCHUNKS, 256, 0, stream>>>(x, y, partial, out);
}